// Round 8
// baseline (90.576 us; speedup 1.0000x reference)
//
#include <hip/hip_runtime.h>
#include <math.h>

// out[n,o] = exp(A)*cos(B)
//   A = sum_i ln(R)*Wr - K*Wi ;  B = sum_i ln(R)*Wi + K*Wr
//   R = fma(|x|, g, 1-g),  K = pi*(x<0)*g,  g = clip(G,0,1)
// n=8192, i=o=128.
//
// R8 = R7 with the copysign sign bug fixed. ps = pi*(x<0) = pi/2 - cs,
// cs = copysign(pi/2, x). Then:
//   A K-term: -ps*g*wi = cs*(+g*wi) - (pi/2)*sum(g*wi)
//   B K-term: +ps*g*wr = cs*(-g*wr) - (pi/2)*sum(-g*wr)
// Both epilogue corrections are -HPI*corr (corrA=sum g*wi, corrB=sum -g*wr).
// Hand-checked x<0,g=1: A += -pi*wi, B += +pi*wr; x>0: both 0. Exact since
// f32(pi) = 2*f32(pi/2) bit-exactly (0x40490FDB = 2x 0x3FC90FDB).
//
// Perf structure (unchanged from R7): LDS holds RAW x only -> 2 broadcast
// ds_read_b128 per i-iter (R3..R6 had 4 -> ~20.5us LDS-pipe floor = the
// 32us plateau). abs via free src modifier; sign via 1 v_and_or_b32.
// Geometry: RPB=8, NT=512 (o:128 x q:4 i-quarters), 1024 blocks x 8 waves,
// launch_bounds(512,8), 16KB LDS.

#define NROWS 8192
#define DIM   128
#define RPB   8
#define NT    512
#define IQ    32
#define LN2_F 0.69314718055994530942f
#define HPI_F 1.57079637050628662109f   // 0x3FC90FDB; 2*HPI == f32(pi)

typedef float v2f __attribute__((ext_vector_type(2)));

static __device__ __forceinline__ v2f vfma2(v2f a, v2f b, v2f c) {
    return __builtin_elementwise_fma(a, b, c);
}
// cs = copysign(pi/2, x) via (x & signbit) | bits(pi/2): one v_and_or_b32.
static __device__ __forceinline__ float csgn(float x) {
    return __int_as_float((__float_as_int(x) & 0x80000000) | 0x3FC90FDB);
}

// wq[i*DIM+o] = (ln2*wr, ln2*wi, g, g/ln2). One-time, 64 blocks.
__global__ __launch_bounds__(256) void prep_w(
    const float* __restrict__ Wr, const float* __restrict__ Wi,
    const float* __restrict__ G, float4* __restrict__ wq)
{
    int t = blockIdx.x * 256 + threadIdx.x;
    if (t < DIM * DIM) {
        float g  = fminf(fmaxf(G[t], 0.0f), 1.0f);
        wq[t] = make_float4(LN2_F * Wr[t], LN2_F * Wi[t], g, g * (1.0f / LN2_F));
    }
}

template <bool PACKED>
__global__ __launch_bounds__(NT, 8) void main_kernel(
    const float* __restrict__ x, const float4* __restrict__ wq,
    const float* __restrict__ Wr, const float* __restrict__ Wi,
    const float* __restrict__ G, float* __restrict__ out)
{
    // 16 KB. Main loop: raw-x plane [DIM][RPB] (4 KB of it).
    // Epilogue overlay: one partial buffer [4][RPB][DIM] (16 KB), A then B.
    __shared__ float sbuf[4 * RPB * DIM];
    float* xpl = sbuf;                 // [DIM][RPB]

    const int tid   = threadIdx.x;
    const int o     = tid & (DIM - 1);
    const int q     = tid >> 7;            // i-quarter 0..3
    const int nbase = blockIdx.x * RPB;
    const float* xb = x + (size_t)nbase * DIM;

    // Stage raw x (1024 floats): float2 coalesced read, SoA scatter.
    {
        float2 v = ((const float2*)xb)[tid];
        int e = tid * 2;
        int i = e & (DIM - 1), r = e >> 7;
        xpl[i * RPB + r]       = v.x;
        xpl[(i + 1) * RPB + r] = v.y;
    }
    __syncthreads();

    v2f accA[4], accB[4];
#pragma unroll
    for (int p = 0; p < 4; ++p) { accA[p] = (v2f){0.f, 0.f}; accB[p] = (v2f){0.f, 0.f}; }
    float corrA = 0.0f, corrB = 0.0f;   // sum(g*wi), sum(-g*wr) over this q

    const int ibase = q * IQ;
#pragma unroll 2
    for (int ii = 0; ii < IQ; ++ii) {
        const int i = ibase + ii;
        float wrl, wil, g, gq;
        if (PACKED) {
            float4 w = wq[i * DIM + o];
            wrl = w.x; wil = w.y; g = w.z; gq = w.w;
        } else {
            g   = fminf(fmaxf(G[i * DIM + o], 0.0f), 1.0f);
            wrl = LN2_F * Wr[i * DIM + o];
            wil = LN2_F * Wi[i * DIM + o];
            gq  = g * (1.0f / LN2_F);
        }
        const float onemg = 1.0f - g;
        const float pgwi  =  gq * wil;     // == +g*wi  (A's cs coefficient)
        const float ngwr  = -gq * wrl;     // == -g*wr  (B's cs coefficient)
        corrA += pgwi;
        corrB += ngwr;
        const v2f wrl2  = {wrl, wrl};
        const v2f wil2  = {wil, wil};
        const v2f pgwi2 = {pgwi, pgwi};
        const v2f ngwr2 = {ngwr, ngwr};

        // 8 rows of raw x via 2 broadcast ds_read_b128.
        const float4* x4 = (const float4*)(xpl + i * RPB);
        float4 x03 = x4[0], x47 = x4[1];

#define ROWPAIR(xa, xb_, idx)                                               \
        do {                                                                \
            float t0 = fmaf(fabsf(xa),  g, onemg);  /* abs src modifier */  \
            float t1 = fmaf(fabsf(xb_), g, onemg);                          \
            v2f l2  = { __log2f(t0), __log2f(t1) };                         \
            v2f cs2 = { csgn(xa), csgn(xb_) };                              \
            accA[idx] = vfma2(l2, wrl2, vfma2(cs2, pgwi2, accA[idx]));      \
            accB[idx] = vfma2(l2, wil2, vfma2(cs2, ngwr2, accB[idx]));      \
        } while (0)

        ROWPAIR(x03.x, x03.y, 0);
        ROWPAIR(x03.z, x03.w, 1);
        ROWPAIR(x47.x, x47.y, 2);
        ROWPAIR(x47.z, x47.w, 3);
#undef ROWPAIR
    }

    // Row-independent corrections: A -= hpi*corrA, B -= hpi*corrB.
    {
        const v2f cA = {-HPI_F * corrA, -HPI_F * corrA};
        const v2f cB = {-HPI_F * corrB, -HPI_F * corrB};
#pragma unroll
        for (int p = 0; p < 4; ++p) { accA[p] += cA; accB[p] += cB; }
    }

    // Epilogue: q-reduce via one 16 KB buffer, A then B (x-plane dead now).
    float* pP = sbuf;                        // [4][RPB][DIM]
    const int c = tid * 2;
    const int r = c >> 7, oo = c & (DIM - 1);

    __syncthreads();   // all waves done reading x-plane
#pragma unroll
    for (int p = 0; p < 4; ++p) {
        pP[q * (RPB * DIM) + (2 * p) * DIM + o]     = accA[p].x;
        pP[q * (RPB * DIM) + (2 * p + 1) * DIM + o] = accA[p].y;
    }
    __syncthreads();
    v2f A = {0.f, 0.f};
#pragma unroll
    for (int qq = 0; qq < 4; ++qq)
        A += *(const v2f*)&pP[qq * (RPB * DIM) + r * DIM + oo];
    __syncthreads();   // before overwriting with B partials
#pragma unroll
    for (int p = 0; p < 4; ++p) {
        pP[q * (RPB * DIM) + (2 * p) * DIM + o]     = accB[p].x;
        pP[q * (RPB * DIM) + (2 * p + 1) * DIM + o] = accB[p].y;
    }
    __syncthreads();
    v2f B = {0.f, 0.f};
#pragma unroll
    for (int qq = 0; qq < 4; ++qq)
        B += *(const v2f*)&pP[qq * (RPB * DIM) + r * DIM + oo];

    float2 res;
    res.x = __expf(A.x) * __cosf(B.x);
    res.y = __expf(A.y) * __cosf(B.y);
    *(float2*)&out[(size_t)(nbase + r) * DIM + oo] = res;
}

extern "C" void kernel_launch(void* const* d_in, const int* in_sizes, int n_in,
                              void* d_out, int out_size, void* d_ws, size_t ws_size,
                              hipStream_t stream) {
    const float* x  = (const float*)d_in[0];
    const float* Wr = (const float*)d_in[1];
    const float* Wi = (const float*)d_in[2];
    const float* G  = (const float*)d_in[3];
    float* out = (float*)d_out;

    const size_t wq_bytes = (size_t)DIM * DIM * sizeof(float4);   // 256 KB
    if (ws_size >= wq_bytes) {
        float4* wq = (float4*)d_ws;
        prep_w<<<(DIM * DIM + 255) / 256, 256, 0, stream>>>(Wr, Wi, G, wq);
        main_kernel<true><<<NROWS / RPB, NT, 0, stream>>>(x, wq,
                                                          nullptr, nullptr, nullptr, out);
    } else {
        main_kernel<false><<<NROWS / RPB, NT, 0, stream>>>(x, nullptr,
                                                           Wr, Wi, G, out);
    }
}

// Round 10
// 89.881 us; speedup vs baseline: 1.0077x; 1.0077x over previous
//
#include <hip/hip_runtime.h>
#include <math.h>

// out[n,o] = exp(A)*cos(B)
//   A = sum_i ln(R)*Wr - K*Wi ;  B = sum_i ln(R)*Wi + K*Wr
//   R = 1 + g*(|x|-1),  K = pi*(x<0)*g,  g = clip(G,0,1)
// n=8192, i=o=128.
//
// R10: K-part offloaded to EXACT-INTEGER i8 MFMA (R9's split-bf16 behaved
// hi-only: absmax 1.72 == hi-only prediction; layout proven right by the
// smallness). wK quantized to 16-bit fixed point, split hi/lo signed i8,
// K = S*(256*sum(s*hi) + sum(s*lo)) via mfma_i32_16x16x64_i8 -- all-integer,
// zero fp rounding. Quant err <= 64*S/2 ~ 3e-4 -> absmax ~0.02-0.1.
// Main loop = R6-minus-K: pair = 1 pk-t + 2 v_log + 2 pk-acc.
// Geometry: RPB=8, NT=512 (o:128 x q:4 i-quarters), 1024 blocks x 8 waves,
// 16KB sbuf + 8KB kbuf.

#define NROWS 8192
#define NPAD  8208        // S rows padded (MFMA reads nbase..nbase+15)
#define DIM   128
#define RPB   8
#define NT    512
#define IQ    32
#define PI_F  3.14159265358979323846f
#define LN2_F 0.69314718055994530942f
#define SA_MAX 0.3150f    // > pi*0.1        (|wA| bound)
#define SB_MAX 0.4825f    // > pi*sqrt(6/256) (|wB| bound)
#define QMAX  32639.0f

typedef float v2f   __attribute__((ext_vector_type(2)));
typedef int   i32x4 __attribute__((ext_vector_type(4)));

static __device__ __forceinline__ v2f vfma2(v2f a, v2f b, v2f c) {
    return __builtin_elementwise_fma(a, b, c);
}

// ---------------------------------------------------------------------------
// prep: wq[i*DIM+o]=(g, ln2*wr, ln2*wi, 0); S8[n][i]=i8(x<0) padded;
// wkf = K-weights as i8 fragments in MFMA B layout:
//   record t=(otile*2+chunk)*64+lane, 64 B each: frag f in {Ahi,Alo,Bhi,Blo},
//   byte e (0..15) <-> k = chunk*64 + (lane>>4)*16 + e, col = otile*16+(lane&15).
//   wA=-pi*g*wi scaled by QMAX/SA_MAX; wB=+pi*g*wr scaled by QMAX/SB_MAX;
//   q split: hi=(q+128)>>8, lo=q-256*hi (both in [-128,127], exact).
// ---------------------------------------------------------------------------
__global__ __launch_bounds__(256) void prep_all(
    const float* __restrict__ x, const float* __restrict__ Wr,
    const float* __restrict__ Wi, const float* __restrict__ G,
    float4* __restrict__ wq, signed char* __restrict__ S8,
    signed char* __restrict__ wkf)
{
    int idx = blockIdx.x * 256 + threadIdx.x;
    int stride = gridDim.x * 256;
    for (int t = idx; t < NPAD * DIM; t += stride) {
        int n = t >> 7;
        S8[t] = (signed char)((n < NROWS && x[t] < 0.0f) ? 1 : 0);
    }
    for (int t = idx; t < DIM * DIM; t += stride) {
        float g = fminf(fmaxf(G[t], 0.0f), 1.0f);
        wq[t] = make_float4(g, LN2_F * Wr[t], LN2_F * Wi[t], 0.0f);
    }
    for (int t = idx; t < 8 * 2 * 64; t += stride) {
        int lane  = t & 63;
        int chunk = (t >> 6) & 1;
        int otile = t >> 7;
        int quad  = lane >> 4;
        int ocol  = otile * 16 + (lane & 15);
        signed char* dst = wkf + (size_t)t * 64;
        for (int e = 0; e < 16; ++e) {
            int k = chunk * 64 + quad * 16 + e;
            float g  = fminf(fmaxf(G[k * DIM + ocol], 0.0f), 1.0f);
            float wA = -PI_F * g * Wi[k * DIM + ocol];
            float wB =  PI_F * g * Wr[k * DIM + ocol];
            int qa = (int)rintf(wA * (QMAX / SA_MAX));
            int qb = (int)rintf(wB * (QMAX / SB_MAX));
            qa = qa < -32639 ? -32639 : (qa > 32639 ? 32639 : qa);
            qb = qb < -32639 ? -32639 : (qb > 32639 ? 32639 : qb);
            int ha = (qa + 128) >> 8, la = qa - (ha << 8);
            int hb = (qb + 128) >> 8, lb = qb - (hb << 8);
            dst[0 * 16 + e] = (signed char)ha;
            dst[1 * 16 + e] = (signed char)la;
            dst[2 * 16 + e] = (signed char)hb;
            dst[3 * 16 + e] = (signed char)lb;
        }
    }
}

__global__ __launch_bounds__(NT, 8) void main_kernel(
    const float* __restrict__ x, const float4* __restrict__ wq,
    const signed char* __restrict__ S8, const signed char* __restrict__ wkf,
    float* __restrict__ out)
{
    // sbuf 16 KB: am1 plane [DIM][RPB] during loop; epilogue overlay = one
    // q-reduce partial buffer [4][RPB][DIM] (A then B). kbuf 8 KB for K.
    __shared__ float  sbuf[4 * RPB * DIM];
    __shared__ float2 kbuf[RPB * DIM];
    float* am1p = sbuf;

    const int tid   = threadIdx.x;
    const int o     = tid & (DIM - 1);
    const int q     = tid >> 7;
    const int nbase = blockIdx.x * RPB;
    const float* xb = x + (size_t)nbase * DIM;

    // Stage am1 plane (1024 floats): float2 coalesced read, SoA scatter.
    {
        float2 v = ((const float2*)xb)[tid];
        int e = tid * 2;
        int i = e & (DIM - 1), r = e >> 7;
        am1p[i * RPB + r]       = fabsf(v.x) - 1.0f;
        am1p[(i + 1) * RPB + r] = fabsf(v.y) - 1.0f;
    }

    // --- K-part via exact i8 MFMA. Wave w = o-tile w (16 cols). ---
    {
        const int lane  = tid & 63;
        const int otile = tid >> 6;
        const int m     = lane & 15;
        const int quad  = lane >> 4;
        const signed char* Sp = S8 + (size_t)(nbase + m) * DIM + quad * 16;
        i32x4 a0 = *(const i32x4*)(Sp);        // chunk 0: k = quad*16+e
        i32x4 a1 = *(const i32x4*)(Sp + 64);   // chunk 1
        const signed char* wb = wkf + ((size_t)(otile * 2) * 64 + lane) * 64;
        const i32x4* w0 = (const i32x4*)wb;            // chunk 0 frags
        const i32x4* w1 = (const i32x4*)(wb + 4096);   // chunk 1 frags
        i32x4 cAh = {0,0,0,0}, cAl = {0,0,0,0}, cBh = {0,0,0,0}, cBl = {0,0,0,0};
        cAh = __builtin_amdgcn_mfma_i32_16x16x64_i8(a0, w0[0], cAh, 0, 0, 0);
        cAl = __builtin_amdgcn_mfma_i32_16x16x64_i8(a0, w0[1], cAl, 0, 0, 0);
        cBh = __builtin_amdgcn_mfma_i32_16x16x64_i8(a0, w0[2], cBh, 0, 0, 0);
        cBl = __builtin_amdgcn_mfma_i32_16x16x64_i8(a0, w0[3], cBl, 0, 0, 0);
        cAh = __builtin_amdgcn_mfma_i32_16x16x64_i8(a1, w1[0], cAh, 0, 0, 0);
        cAl = __builtin_amdgcn_mfma_i32_16x16x64_i8(a1, w1[1], cAl, 0, 0, 0);
        cBh = __builtin_amdgcn_mfma_i32_16x16x64_i8(a1, w1[2], cBh, 0, 0, 0);
        cBl = __builtin_amdgcn_mfma_i32_16x16x64_i8(a1, w1[3], cBl, 0, 0, 0);
        const int ocol = otile * 16 + m;   // C/D: col=lane&15, row=quad*4+reg
#pragma unroll
        for (int r = 0; r < 4; ++r) {
            int row = quad * 4 + r;
            if (row < RPB) {
                float kA = (SA_MAX / QMAX) * fmaf(256.0f, (float)cAh[r], (float)cAl[r]);
                float kB = (SB_MAX / QMAX) * fmaf(256.0f, (float)cBh[r], (float)cBl[r]);
                kbuf[row * DIM + ocol] = make_float2(kA, kB);
            }
        }
    }
    __syncthreads();

    v2f accA[4], accB[4];
#pragma unroll
    for (int p = 0; p < 4; ++p) { accA[p] = (v2f){0.f, 0.f}; accB[p] = (v2f){0.f, 0.f}; }

    const int ibase = q * IQ;
#pragma unroll 2
    for (int ii = 0; ii < IQ; ++ii) {
        const int i = ibase + ii;
        float4 w = wq[i * DIM + o];       // (g, ln2*wr, ln2*wi, -)
        const v2f gg2  = {w.x, w.x};
        const v2f wrl2 = {w.y, w.y};
        const v2f wil2 = {w.z, w.z};

        const float4* a4 = (const float4*)(am1p + i * RPB);
        float4 a03 = a4[0], a47 = a4[1];  // 2 broadcast ds_read_b128

#define PAIR(mx, my, idx)                                                   \
        do {                                                                \
            v2f t2 = vfma2((v2f){mx, my}, gg2, (v2f){1.0f, 1.0f});          \
            v2f l2 = { __log2f(t2.x), __log2f(t2.y) };                      \
            accA[idx] = vfma2(l2, wrl2, accA[idx]);                         \
            accB[idx] = vfma2(l2, wil2, accB[idx]);                         \
        } while (0)

        PAIR(a03.x, a03.y, 0);
        PAIR(a03.z, a03.w, 1);
        PAIR(a47.x, a47.y, 2);
        PAIR(a47.z, a47.w, 3);
#undef PAIR
    }

    // Epilogue: q-reduce (one 16 KB buffer, A then B), merge K, exp*cos.
    float* pP = sbuf;                         // [4][RPB][DIM], overlays am1p
    const int c2 = tid * 2;
    const int rr = c2 >> 7, oo = c2 & (DIM - 1);

    __syncthreads();   // everyone done reading am1 plane
#pragma unroll
    for (int p = 0; p < 4; ++p) {
        pP[q * (RPB * DIM) + (2 * p) * DIM + o]     = accA[p].x;
        pP[q * (RPB * DIM) + (2 * p + 1) * DIM + o] = accA[p].y;
    }
    __syncthreads();
    v2f A = {0.f, 0.f};
#pragma unroll
    for (int qq = 0; qq < 4; ++qq)
        A += *(const v2f*)&pP[qq * (RPB * DIM) + rr * DIM + oo];
    __syncthreads();
#pragma unroll
    for (int p = 0; p < 4; ++p) {
        pP[q * (RPB * DIM) + (2 * p) * DIM + o]     = accB[p].x;
        pP[q * (RPB * DIM) + (2 * p + 1) * DIM + o] = accB[p].y;
    }
    __syncthreads();
    v2f B = {0.f, 0.f};
#pragma unroll
    for (int qq = 0; qq < 4; ++qq)
        B += *(const v2f*)&pP[qq * (RPB * DIM) + rr * DIM + oo];

    float2 k0 = kbuf[rr * DIM + oo];
    float2 k1 = kbuf[rr * DIM + oo + 1];
    float2 res;
    res.x = __expf(A.x + k0.x) * __cosf(B.x + k0.y);
    res.y = __expf(A.y + k1.x) * __cosf(B.y + k1.y);
    *(float2*)&out[(size_t)(nbase + rr) * DIM + oo] = res;
}

// Fallback (ws too small): simple correct version.
__global__ __launch_bounds__(128) void fallback_kernel(
    const float* __restrict__ x, const float* __restrict__ Wr,
    const float* __restrict__ Wi, const float* __restrict__ G,
    float* __restrict__ out)
{
    const int o = threadIdx.x;
    const int nbase = blockIdx.x * RPB;
    float accA[RPB], accB[RPB];
#pragma unroll
    for (int r = 0; r < RPB; ++r) { accA[r] = 0.f; accB[r] = 0.f; }
    for (int i = 0; i < DIM; ++i) {
        float g  = fminf(fmaxf(G[i * DIM + o], 0.0f), 1.0f);
        float wr = Wr[i * DIM + o], wi = Wi[i * DIM + o];
#pragma unroll
        for (int r = 0; r < RPB; ++r) {
            float xv = x[(size_t)(nbase + r) * DIM + i];
            float t  = fmaf(fabsf(xv) - 1.0f, g, 1.0f);
            float l  = __log2f(t) * LN2_F;
            float ps = (xv < 0.0f) ? (PI_F * g) : 0.0f;
            accA[r] += l * wr - ps * wi;
            accB[r] += l * wi + ps * wr;
        }
    }
#pragma unroll
    for (int r = 0; r < RPB; ++r)
        out[(size_t)(nbase + r) * DIM + o] = __expf(accA[r]) * __cosf(accB[r]);
}

extern "C" void kernel_launch(void* const* d_in, const int* in_sizes, int n_in,
                              void* d_out, int out_size, void* d_ws, size_t ws_size,
                              hipStream_t stream) {
    const float* x  = (const float*)d_in[0];
    const float* Wr = (const float*)d_in[1];
    const float* Wi = (const float*)d_in[2];
    const float* G  = (const float*)d_in[3];
    float* out = (float*)d_out;

    const size_t wq_bytes  = (size_t)DIM * DIM * sizeof(float4);   // 256 KB
    const size_t S_bytes   = (size_t)NPAD * DIM;                   // ~1.05 MB
    const size_t wkf_bytes = (size_t)8 * 2 * 64 * 64;              // 64 KB
    if (ws_size >= wq_bytes + S_bytes + wkf_bytes) {
        float4*      wq  = (float4*)d_ws;
        signed char* S8  = (signed char*)((char*)d_ws + wq_bytes);
        signed char* wkf = (signed char*)((char*)d_ws + wq_bytes + S_bytes);
        prep_all<<<(NPAD * DIM + 255) / 256, 256, 0, stream>>>(x, Wr, Wi, G, wq, S8, wkf);
        main_kernel<<<NROWS / RPB, NT, 0, stream>>>(x, wq, S8, wkf, out);
    } else {
        fallback_kernel<<<NROWS / RPB, 128, 0, stream>>>(x, Wr, Wi, G, out);
    }
}

// Round 11
// 85.223 us; speedup vs baseline: 1.0628x; 1.0547x over previous
//
#include <hip/hip_runtime.h>
#include <math.h>

// out[n,o] = exp(A)*cos(B)
//   A = sum_i ln(R)*Wr - K*Wi ;  B = sum_i ln(R)*Wi + K*Wr
//   R = 1 + g*(|x|-1),  K = pi*(x<0)*g,  g = clip(G,0,1)
// n=8192, i=o=128.
//
// R11 = R6 (best verified: 85.4us total, absmax 0.0156) + explicit SW
// pipelining of the per-iter global wq load (L2-hit ~200cy, previously
// issued+used in the same iteration). Prefetch wq[(ii+1)&31] one iter ahead
// (wrap keeps it in-bounds; last-iter prefetch is a harmless reload).
// MFMA K-offload abandoned: R9/R10 cost margin (absmax 1.31) + overhead for
// a 2-pkfma/pair saving.
// Geometry: RPB=8, NT=512 (o:128 x q:4 i-quarters), 1024 blocks x 8 waves,
// launch_bounds(512,8), 16KB LDS (am1+ps planes -> epilogue overlay).

#define NROWS 8192
#define DIM   128
#define RPB   8
#define NT    512
#define IQ    32
#define PI_F  3.14159265358979323846f
#define LN2_F 0.69314718055994530942f

typedef float v2f __attribute__((ext_vector_type(2)));

static __device__ __forceinline__ v2f vfma2(v2f a, v2f b, v2f c) {
    return __builtin_elementwise_fma(a, b, c);
}

// wq[i*DIM+o] = (ln2*wr, ln2*wi, g, g/ln2). One-time, 64 blocks.
__global__ __launch_bounds__(256) void prep_w(
    const float* __restrict__ Wr, const float* __restrict__ Wi,
    const float* __restrict__ G, float4* __restrict__ wq)
{
    int t = blockIdx.x * 256 + threadIdx.x;
    if (t < DIM * DIM) {
        float g  = fminf(fmaxf(G[t], 0.0f), 1.0f);
        wq[t] = make_float4(LN2_F * Wr[t], LN2_F * Wi[t], g, g * (1.0f / LN2_F));
    }
}

template <bool PACKED>
__global__ __launch_bounds__(NT, 8) void main_kernel(
    const float* __restrict__ x, const float4* __restrict__ wq,
    const float* __restrict__ Wr, const float* __restrict__ Wi,
    const float* __restrict__ G, float* __restrict__ out)
{
    // 16 KB. Main loop: am1 plane + ps plane [DIM][RPB] each (8 KB).
    // Epilogue overlay: one partial buffer [4][RPB][DIM] (16 KB), A then B.
    __shared__ float sbuf[4 * RPB * DIM];
    float* am1p = sbuf;               // [DIM][RPB]
    float* psp  = sbuf + DIM * RPB;   // [DIM][RPB]

    const int tid   = threadIdx.x;
    const int o     = tid & (DIM - 1);
    const int q     = tid >> 7;            // i-quarter 0..3
    const int nbase = blockIdx.x * RPB;
    const float* xb = x + (size_t)nbase * DIM;

    // Stage x tile (1024 floats): float2 coalesced read, SoA scatter.
    {
        float2 v = ((const float2*)xb)[tid];
        int e = tid * 2;
        int i = e & (DIM - 1), r = e >> 7;
        am1p[i * RPB + r]       = fabsf(v.x) - 1.0f;
        am1p[(i + 1) * RPB + r] = fabsf(v.y) - 1.0f;
        psp[i * RPB + r]        = (v.x < 0.0f) ? PI_F : 0.0f;
        psp[(i + 1) * RPB + r]  = (v.y < 0.0f) ? PI_F : 0.0f;
    }
    __syncthreads();

    v2f accA[4], accB[4];
#pragma unroll
    for (int p = 0; p < 4; ++p) { accA[p] = (v2f){0.f, 0.f}; accB[p] = (v2f){0.f, 0.f}; }

    const int ibase = q * IQ;
    const float4* wqp = PACKED ? (wq + ibase * DIM + o) : nullptr;

    // Software pipeline: weight for iteration ii prefetched at ii-1.
    float4 wcur;
    if (PACKED) wcur = wqp[0];

#pragma unroll 2
    for (int ii = 0; ii < IQ; ++ii) {
        const int i = ibase + ii;
        float wrl, wil, g, gq;
        float4 wnxt;
        if (PACKED) {
            wnxt = wqp[((ii + 1) & (IQ - 1)) * DIM];   // prefetch (wraps, in-bounds)
            wrl = wcur.x; wil = wcur.y; g = wcur.z; gq = wcur.w;
        } else {
            g   = fminf(fmaxf(G[i * DIM + o], 0.0f), 1.0f);
            wrl = LN2_F * Wr[i * DIM + o];
            wil = LN2_F * Wi[i * DIM + o];
            gq  = g * (1.0f / LN2_F);
        }
        const float ngwi = -gq * wil;     // == -g*wi
        const float gwr  =  gq * wrl;     // ==  g*wr
        const v2f gg2   = {g, g};
        const v2f wrl2  = {wrl, wrl};
        const v2f wil2  = {wil, wil};
        const v2f ngwi2 = {ngwi, ngwi};
        const v2f gwr2  = {gwr, gwr};
        const v2f one2  = {1.0f, 1.0f};

        // 8 rows via 2+2 broadcast ds_read_b128 (all lanes same address).
        const float4* a4 = (const float4*)(am1p + i * RPB);
        const float4* p4 = (const float4*)(psp  + i * RPB);
        float4 a03 = a4[0], a47 = a4[1];
        float4 s03 = p4[0], s47 = p4[1];

#define ROWPAIR(mx, my, sx, sy, idx)                                        \
        do {                                                                \
            v2f t2 = vfma2((v2f){mx, my}, gg2, one2);                       \
            v2f l2 = { __log2f(t2.x), __log2f(t2.y) };                      \
            v2f s2 = {sx, sy};                                              \
            accA[idx] = vfma2(l2, wrl2, vfma2(s2, ngwi2, accA[idx]));       \
            accB[idx] = vfma2(l2, wil2, vfma2(s2, gwr2,  accB[idx]));       \
        } while (0)

        ROWPAIR(a03.x, a03.y, s03.x, s03.y, 0);
        ROWPAIR(a03.z, a03.w, s03.z, s03.w, 1);
        ROWPAIR(a47.x, a47.y, s47.x, s47.y, 2);
        ROWPAIR(a47.z, a47.w, s47.z, s47.w, 3);
#undef ROWPAIR

        if (PACKED) wcur = wnxt;
    }

    // Epilogue: q-reduce via one 16 KB buffer, A then B (planes dead now).
    float* pP = sbuf;                        // [4][RPB][DIM]
    const int c = tid * 2;
    const int r = c >> 7, oo = c & (DIM - 1);

    __syncthreads();   // all waves done reading planes
#pragma unroll
    for (int p = 0; p < 4; ++p) {
        pP[q * (RPB * DIM) + (2 * p) * DIM + o]     = accA[p].x;
        pP[q * (RPB * DIM) + (2 * p + 1) * DIM + o] = accA[p].y;
    }
    __syncthreads();
    v2f A = {0.f, 0.f};
#pragma unroll
    for (int qq = 0; qq < 4; ++qq)
        A += *(const v2f*)&pP[qq * (RPB * DIM) + r * DIM + oo];
    __syncthreads();   // before overwriting with B partials
#pragma unroll
    for (int p = 0; p < 4; ++p) {
        pP[q * (RPB * DIM) + (2 * p) * DIM + o]     = accB[p].x;
        pP[q * (RPB * DIM) + (2 * p + 1) * DIM + o] = accB[p].y;
    }
    __syncthreads();
    v2f B = {0.f, 0.f};
#pragma unroll
    for (int qq = 0; qq < 4; ++qq)
        B += *(const v2f*)&pP[qq * (RPB * DIM) + r * DIM + oo];

    float2 res;
    res.x = __expf(A.x) * __cosf(B.x);
    res.y = __expf(A.y) * __cosf(B.y);
    *(float2*)&out[(size_t)(nbase + r) * DIM + oo] = res;
}

extern "C" void kernel_launch(void* const* d_in, const int* in_sizes, int n_in,
                              void* d_out, int out_size, void* d_ws, size_t ws_size,
                              hipStream_t stream) {
    const float* x  = (const float*)d_in[0];
    const float* Wr = (const float*)d_in[1];
    const float* Wi = (const float*)d_in[2];
    const float* G  = (const float*)d_in[3];
    float* out = (float*)d_out;

    const size_t wq_bytes = (size_t)DIM * DIM * sizeof(float4);   // 256 KB
    if (ws_size >= wq_bytes) {
        float4* wq = (float4*)d_ws;
        prep_w<<<(DIM * DIM + 255) / 256, 256, 0, stream>>>(Wr, Wi, G, wq);
        main_kernel<true><<<NROWS / RPB, NT, 0, stream>>>(x, wq,
                                                          nullptr, nullptr, nullptr, out);
    } else {
        main_kernel<false><<<NROWS / RPB, NT, 0, stream>>>(x, nullptr,
                                                           Wr, Wi, G, out);
    }
}